// Round 8
// baseline (377.809 us; speedup 1.0000x reference)
//
#include <hip/hip_runtime.h>

// Per-row MLP 5->120->84->5 + relu + L2-normalize + x!=0 mask.
// R8: R7 minus all weight-LDS. Weight B-frags are read per-lane directly
// from the packed global copies (36 KB total: L1/L2-resident, re-read per
// wave). LDS is only the per-wave 4 KB activation transpose buffer, reused
// for h1 then h2 (sequential phases within a wave; no block barrier at all).
// LDS 63.5 KB -> 18.5 KB; launch_bounds(256,4) -> 4 waves/SIMD.
// Rescue kernel: grid-stride + row<nrows guard (rocprof dispatch-replay can
// present stale cnt/list; guard prevents OOB in that mode).

typedef _Float16 f16x8 __attribute__((ext_vector_type(8)));
typedef float    f32x4 __attribute__((ext_vector_type(4)));

#define CNT_OFF  0
#define W2T_OFF  64
#define W1P_OFF  40384
#define W2P_OFF  48576
#define W3P_OFF  73152
#define LIST_OFF 77312
#define TAU2     0.0625f   // rescue if ||y||^2 < 0.25^2

// ---------------- pack ----------------
__global__ __launch_bounds__(256) void pack_kernel(
    const float* __restrict__ W1, const float* __restrict__ W2,
    const float* __restrict__ W3, char* __restrict__ ws)
{
    int i = blockIdx.x * 256 + threadIdx.x;
    if (i == 0) *(unsigned int*)(ws + CNT_OFF) = 0u;
    _Float16* W1p = (_Float16*)(ws + W1P_OFF);   // [128][32]
    _Float16* W2p = (_Float16*)(ws + W2P_OFF);   // [96][128]
    _Float16* W3p = (_Float16*)(ws + W3P_OFF);   // [16][128]
    float*    W2T = (float*)(ws + W2T_OFF);      // [120][84]
    if (i < 4096)  { int r = i >> 5, k = i & 31;
        W1p[i] = (_Float16)((r < 120 && k < 5)   ? W1[r*5 + k]    : 0.f); }
    if (i < 12288) { int r = i >> 7, k = i & 127;
        W2p[i] = (_Float16)((r < 84  && k < 120) ? W2[r*120 + k]  : 0.f); }
    if (i < 2048)  { int r = i >> 7, k = i & 127;
        W3p[i] = (_Float16)((r < 5   && k < 84)  ? W3[r*84 + k]   : 0.f); }
    if (i < 10080) { int g = i / 120, h = i - g*120; W2T[h*84 + g] = W2[i]; }
}

// ---------------- main (MFMA) ----------------
__global__ __launch_bounds__(256, 4) void mfma_main(
    const float* __restrict__ x, const float* __restrict__ b1,
    const float* __restrict__ b2, const float* __restrict__ b3,
    const char* __restrict__ ws, float* __restrict__ out,
    unsigned int* __restrict__ cnt, unsigned int* __restrict__ list,
    unsigned int cap, int nrows)
{
    __shared__ __align__(16) _Float16 sh[4][16 * 128];  // 16 KB: per-wave h1/h2
    __shared__ __align__(16) float    sy[4][16 * 8];    //  2 KB

    const _Float16* W1p = (const _Float16*)(ws + W1P_OFF);
    const _Float16* W2p = (const _Float16*)(ws + W2P_OFF);
    const _Float16* W3p = (const _Float16*)(ws + W3P_OFF);

    const int tid = threadIdx.x;
    const int w = tid >> 6, lane = tid & 63;
    const int col = lane & 15, q = lane >> 4;
    const long rowbase = (long)blockIdx.x * 64 + w * 16;
    char* shw = (char*)sh[w];

    // per-lane biases (masked at padding)
    float b1v[8], b2v[6], b3v;
#pragma unroll
    for (int n = 0; n < 8; ++n) { int f = n*16 + col; b1v[n] = (f < 120) ? b1[f] : 0.f; }
#pragma unroll
    for (int n = 0; n < 6; ++n) { int f = n*16 + col; b2v[n] = (f < 84)  ? b2[f] : 0.f; }
    b3v = (col < 5) ? b3[col] : 0.f;

    // x A-frag: row = lane&15, k = q*8+j (k>=5 zero)
    f16x8 ax;
#pragma unroll
    for (int j = 0; j < 8; ++j) ax[j] = (_Float16)0.f;
    {
        const long grow0 = rowbase + col;
        if (q == 0 && grow0 < nrows) {
            const float* xp = x + grow0 * 5;
            ax[0] = (_Float16)xp[0]; ax[1] = (_Float16)xp[1];
            ax[2] = (_Float16)xp[2]; ax[3] = (_Float16)xp[3];
            ax[4] = (_Float16)xp[4];
        }
    }

    // ---- L1: h1[16x120] = relu(x @ W1^T + b1) -> f16 into shw ----
#pragma unroll
    for (int n = 0; n < 8; ++n) {
        f16x8 bf = *(const f16x8*)(W1p + ((n*16 + col) * 32 + q * 8));
        f32x4 c = __builtin_amdgcn_mfma_f32_16x16x32_f16(
            ax, bf, (f32x4){0.f, 0.f, 0.f, 0.f}, 0, 0, 0);
#pragma unroll
        for (int j = 0; j < 4; ++j) {
            float v = fmaxf(c[j] + b1v[n], 0.f);
            int r = q*4 + j;
            *(_Float16*)(shw + r*256 + ((((n*16 + col)) * 2) ^ ((r & 7) << 4))) =
                (_Float16)v;
        }
    }

    // ---- L2: h2[16x84] = relu(h1 @ W2^T + b2), B-frags from global ----
    f32x4 acc[6];
#pragma unroll
    for (int n = 0; n < 6; ++n) acc[n] = (f32x4){0.f, 0.f, 0.f, 0.f};
#pragma unroll
    for (int t = 0; t < 4; ++t) {
        f16x8 af = *(const f16x8*)(shw + col*256 +
                                   ((t*64 + q*16) ^ ((col & 7) << 4)));
#pragma unroll
        for (int n = 0; n < 6; ++n) {
            f16x8 bf = *(const f16x8*)(W2p + ((n*16 + col) * 128 + t*32 + q*8));
            acc[n] = __builtin_amdgcn_mfma_f32_16x16x32_f16(af, bf, acc[n], 0, 0, 0);
        }
    }
    // h2 -> shw (reuses the h1 buffer; all h1 reads above precede these writes)
#pragma unroll
    for (int n = 0; n < 6; ++n) {
#pragma unroll
        for (int j = 0; j < 4; ++j) {
            float v = fmaxf(acc[n][j] + b2v[n], 0.f);
            int r = q*4 + j;
            *(_Float16*)(shw + r*256 + ((((n*16 + col)) * 2) ^ ((r & 7) << 4))) =
                (_Float16)v;
        }
    }

    // ---- L3: y[16x5] = relu(h2 @ W3^T + b3), B-frags from global ----
    f32x4 acy = (f32x4){0.f, 0.f, 0.f, 0.f};
#pragma unroll
    for (int t = 0; t < 3; ++t) {
        f16x8 af = *(const f16x8*)(shw + col*256 +
                                   ((t*64 + q*16) ^ ((col & 7) << 4)));
        f16x8 bf = *(const f16x8*)(W3p + (col * 128 + t*32 + q*8));
        acy = __builtin_amdgcn_mfma_f32_16x16x32_f16(af, bf, acy, 0, 0, 0);
    }
    if (col < 5) {
#pragma unroll
        for (int j = 0; j < 4; ++j)
            sy[w][(q*4 + j) * 8 + col] = fmaxf(acy[j] + b3v, 0.f);
    }

    // ---- epilogue: normalize + mask + rescue flag (lanes 0..15) ----
    if (lane < 16) {
        long grow = rowbase + lane;
        if (grow < nrows) {
            float y0 = sy[w][lane*8 + 0], y1 = sy[w][lane*8 + 1],
                  y2 = sy[w][lane*8 + 2], y3 = sy[w][lane*8 + 3],
                  y4 = sy[w][lane*8 + 4];
            float ss = y0*y0 + y1*y1 + y2*y2 + y3*y3 + y4*y4;
            float inv = 1.0f / fmaxf(sqrtf(ss), 1e-12f);
            const float* xp = x + grow * 5;
            float* op = out + grow * 5;
            op[0] = (xp[0] != 0.f) ? 0.f : y0 * inv;
            op[1] = (xp[1] != 0.f) ? 0.f : y1 * inv;
            op[2] = (xp[2] != 0.f) ? 0.f : y2 * inv;
            op[3] = (xp[3] != 0.f) ? 0.f : y3 * inv;
            op[4] = (xp[4] != 0.f) ? 0.f : y4 * inv;
            if (ss < TAU2) {
                unsigned int idx = atomicAdd(cnt, 1u);
                if (idx < cap) list[idx] = (unsigned int)grow;
            }
        }
    }
}

// ---------------- rescue (exact f32, R3 structure) ----------------
template <int G0>
__device__ __forceinline__ void half_pass(
    const float xv[5],
    const float* __restrict__ W1, const float* __restrict__ b1,
    const float* __restrict__ W2T, const float* __restrict__ b2,
    const float* __restrict__ W3,
    float y[5])
{
    float acc[42];
#pragma unroll
    for (int g = 0; g < 42; ++g) acc[g] = b2[G0 + g];
    for (int h = 0; h < 120; ++h) {
        float a = b1[h];
        a = fmaf(W1[h*5 + 0], xv[0], a);
        a = fmaf(W1[h*5 + 1], xv[1], a);
        a = fmaf(W1[h*5 + 2], xv[2], a);
        a = fmaf(W1[h*5 + 3], xv[3], a);
        a = fmaf(W1[h*5 + 4], xv[4], a);
        a = fmaxf(a, 0.0f);
        const float* wr = W2T + h*84 + G0;
#pragma unroll
        for (int g = 0; g < 42; ++g) acc[g] = fmaf(wr[g], a, acc[g]);
    }
#pragma unroll
    for (int g = 0; g < 42; ++g) acc[g] = fmaxf(acc[g], 0.0f);
#pragma unroll
    for (int o = 0; o < 5; ++o) {
        const float* w3o = W3 + o*84 + G0;
        float t = y[o];
#pragma unroll
        for (int g = 0; g < 42; ++g) t = fmaf(w3o[g], acc[g], t);
        y[o] = t;
    }
}

__global__ __launch_bounds__(256) void rescue_kernel(
    const float* __restrict__ x,
    const float* __restrict__ W1, const float* __restrict__ b1,
    const char*  __restrict__ ws, const float* __restrict__ b2,
    const float* __restrict__ W3, const float* __restrict__ b3,
    float* __restrict__ out, unsigned int cap, int nrows)
{
    const unsigned int* cnt  = (const unsigned int*)(ws + CNT_OFF);
    const unsigned int* list = (const unsigned int*)(ws + LIST_OFF);
    const float* W2T = (const float*)(ws + W2T_OFF);
    unsigned int count = *cnt;
    if (count > cap) count = cap;

    for (unsigned int t = blockIdx.x * 256 + threadIdx.x;
         t < count; t += gridDim.x * 256) {
        long row = (long)list[t];
        if (row < 0 || row >= (long)nrows) continue;   // replay-safety guard

        const float* xr = x + row * 5;
        float xv[5];
#pragma unroll
        for (int i = 0; i < 5; ++i) xv[i] = xr[i];

        float y[5];
#pragma unroll
        for (int o = 0; o < 5; ++o) y[o] = b3[o];
        half_pass<0>(xv, W1, b1, W2T, b2, W3, y);
        half_pass<42>(xv, W1, b1, W2T, b2, W3, y);
#pragma unroll
        for (int o = 0; o < 5; ++o) y[o] = fmaxf(y[o], 0.0f);

        float ss = y[0]*y[0];
        ss = fmaf(y[1], y[1], ss);
        ss = fmaf(y[2], y[2], ss);
        ss = fmaf(y[3], y[3], ss);
        ss = fmaf(y[4], y[4], ss);
        float inv = 1.0f / fmaxf(sqrtf(ss), 1e-12f);
        float* op = out + row * 5;
#pragma unroll
        for (int o = 0; o < 5; ++o)
            op[o] = (xv[o] != 0.f) ? 0.f : y[o] * inv;
    }
}

// ---------------- launch ----------------
extern "C" void kernel_launch(void* const* d_in, const int* in_sizes, int n_in,
                              void* d_out, int out_size, void* d_ws, size_t ws_size,
                              hipStream_t stream) {
    const float* x  = (const float*)d_in[0];
    const float* W1 = (const float*)d_in[1];
    const float* b1 = (const float*)d_in[2];
    const float* W2 = (const float*)d_in[3];
    const float* b2 = (const float*)d_in[4];
    const float* W3 = (const float*)d_in[5];
    const float* b3 = (const float*)d_in[6];
    float* out = (float*)d_out;
    char* ws = (char*)d_ws;

    const int nrows = in_sizes[0] / 5;
    unsigned int cap = (ws_size > (size_t)LIST_OFF + 4)
                       ? (unsigned int)((ws_size - LIST_OFF) / 4) : 0u;
    unsigned int* cnt  = (unsigned int*)(ws + CNT_OFF);
    unsigned int* list = (unsigned int*)(ws + LIST_OFF);

    pack_kernel<<<48, 256, 0, stream>>>(W1, W2, W3, ws);

    const int mblocks = (nrows + 63) / 64;
    mfma_main<<<mblocks, 256, 0, stream>>>(x, b1, b2, b3, ws, out,
                                           cnt, list, cap, nrows);

    rescue_kernel<<<256, 256, 0, stream>>>(x, W1, b1, ws, b2, W3, b3,
                                           out, cap, nrows);
}

// Round 9
// 173.644 us; speedup vs baseline: 2.1758x; 2.1758x over previous
//
#include <hip/hip_runtime.h>

// Per-row MLP 5->120->84->5 + relu + L2-normalize + x!=0 mask.
// R9: persistent-wave MFMA kernel.
//  - W1/W3 B-frags + biases: registers, loaded ONCE per wave (44 VGPR).
//  - W2: f16 in LDS, staged ONCE per block, 272B row stride (conflict-light
//    ds_read_b128 B-frags, no swizzle needed). One barrier per block total.
//  - per-wave act buffer [16][136 f16] (272B stride), reused h1 -> h2.
//  - grid-stride loop: 768 blocks (3/CU co-resident), ~27 tiles per wave,
//    so per-wave/per-block setup amortizes (R8's fatal per-tile cost).
//  - bias via MFMA C-init. Rescue list for ||y|| < 0.25 rows (f32 recompute).

typedef _Float16 f16x8 __attribute__((ext_vector_type(8)));
typedef float    f32x4 __attribute__((ext_vector_type(4)));

#define CNT_OFF  0
#define W2T_OFF  64          // f32[120*84]  -> ends 40384
#define W1P_OFF  40384       // f16[128][32] -> ends 48576
#define W2P_OFF  48576       // f16[96][128] -> ends 73152
#define W3P_OFF  73152       // f16[16][128] -> ends 77248
#define LIST_OFF 77248
#define TAU2     0.0625f     // rescue if ||y||^2 < 0.25^2

// ---------------- pack ----------------
__global__ __launch_bounds__(256) void pack_kernel(
    const float* __restrict__ W1, const float* __restrict__ W2,
    const float* __restrict__ W3, char* __restrict__ ws)
{
    int i = blockIdx.x * 256 + threadIdx.x;
    if (i == 0) *(unsigned int*)(ws + CNT_OFF) = 0u;
    _Float16* W1p = (_Float16*)(ws + W1P_OFF);
    _Float16* W2p = (_Float16*)(ws + W2P_OFF);
    _Float16* W3p = (_Float16*)(ws + W3P_OFF);
    float*    W2T = (float*)(ws + W2T_OFF);
    if (i < 4096)  { int r = i >> 5, k = i & 31;
        W1p[i] = (_Float16)((r < 120 && k < 5)   ? W1[r*5 + k]   : 0.f); }
    if (i < 12288) { int r = i >> 7, k = i & 127;
        W2p[i] = (_Float16)((r < 84  && k < 120) ? W2[r*120 + k] : 0.f); }
    if (i < 2048)  { int r = i >> 7, k = i & 127;
        W3p[i] = (_Float16)((r < 5   && k < 84)  ? W3[r*84 + k]  : 0.f); }
    if (i < 10080) { int g = i / 120, h = i - g*120; W2T[h*84 + g] = W2[i]; }
}

// ---------------- main (persistent MFMA) ----------------
__global__ __launch_bounds__(256, 3) void mfma_main(
    const float* __restrict__ x, const float* __restrict__ b1,
    const float* __restrict__ b2, const float* __restrict__ b3,
    const char* __restrict__ ws, float* __restrict__ out,
    unsigned int* __restrict__ cnt, unsigned int* __restrict__ list,
    unsigned int cap, int nrows, int ntiles)
{
    __shared__ __align__(16) char  sW2[96 * 272];       // 25.5 KB, block-shared
    __shared__ __align__(16) char  sact_[4][16 * 272];  // 17 KB, per-wave
    __shared__ __align__(16) float sy_[4][16 * 6];      // 1.5 KB, per-wave

    const _Float16* W1p = (const _Float16*)(ws + W1P_OFF);
    const _Float16* W2p = (const _Float16*)(ws + W2P_OFF);
    const _Float16* W3p = (const _Float16*)(ws + W3P_OFF);

    const int tid = threadIdx.x;
    // stage W2 -> LDS once per block, repack row stride 128 -> 136 f16 (272B)
    for (int c = tid; c < 1536; c += 256) {
        int r = c >> 4, s = c & 15;
        *(float4*)(sW2 + r*272 + s*16) = *(const float4*)(W2p + r*128 + s*8);
    }
    __syncthreads();

    const int w = tid >> 6, lane = tid & 63;
    const int col = lane & 15, q = lane >> 4;
    _Float16* act = (_Float16*)(sact_[w]);
    float* syw = sy_[w];

    // ---- persistent per-lane weight fragments & biases ----
    f16x8 w1f[8], w3f[3];
#pragma unroll
    for (int n = 0; n < 8; ++n)
        w1f[n] = *(const f16x8*)(W1p + (n*16 + col)*32 + q*8);
#pragma unroll
    for (int t3 = 0; t3 < 3; ++t3)
        w3f[t3] = *(const f16x8*)(W3p + col*128 + t3*32 + q*8);
    float b1v[8], b2v[6], b3v;
#pragma unroll
    for (int n = 0; n < 8; ++n) { int f = n*16 + col; b1v[n] = (f < 120) ? b1[f] : 0.f; }
#pragma unroll
    for (int n = 0; n < 6; ++n) { int f = n*16 + col; b2v[n] = (f < 84)  ? b2[f] : 0.f; }
    b3v = (col < 5) ? b3[col] : 0.f;

    const int gw = blockIdx.x * 4 + w;
    const int nw = gridDim.x * 4;
    for (int t = gw; t < ntiles; t += nw) {
        const long rowbase = (long)t * 16;

        // x A-frag: row = lane&15, k = q*8+j (k>=5 zero)
        f16x8 ax;
#pragma unroll
        for (int j = 0; j < 8; ++j) ax[j] = (_Float16)0.f;
        if (q == 0) {
            long r0 = rowbase + col;
            if (r0 < nrows) {
                const float* xp = x + r0 * 5;
                ax[0] = (_Float16)xp[0]; ax[1] = (_Float16)xp[1];
                ax[2] = (_Float16)xp[2]; ax[3] = (_Float16)xp[3];
                ax[4] = (_Float16)xp[4];
            }
        }

        // ---- L1: h1 = relu(x @ W1^T + b1) -> act (f16, [row][feat]) ----
#pragma unroll
        for (int n = 0; n < 8; ++n) {
            f32x4 c; c[0] = b1v[n]; c[1] = b1v[n]; c[2] = b1v[n]; c[3] = b1v[n];
            c = __builtin_amdgcn_mfma_f32_16x16x32_f16(ax, w1f[n], c, 0, 0, 0);
#pragma unroll
            for (int j = 0; j < 4; ++j)
                act[(q*4 + j)*136 + n*16 + col] = (_Float16)fmaxf(c[j], 0.f);
        }

        // ---- L2: h2 = relu(h1 @ W2^T + b2), B-frags from block LDS ----
        f32x4 acc[6];
#pragma unroll
        for (int n = 0; n < 6; ++n) {
            acc[n][0] = b2v[n]; acc[n][1] = b2v[n];
            acc[n][2] = b2v[n]; acc[n][3] = b2v[n];
        }
#pragma unroll
        for (int t4 = 0; t4 < 4; ++t4) {
            f16x8 af = *(const f16x8*)((const char*)act + col*272 + t4*64 + q*16);
#pragma unroll
            for (int n = 0; n < 6; ++n) {
                f16x8 bf = *(const f16x8*)(sW2 + (n*16 + col)*272 + t4*64 + q*16);
                acc[n] = __builtin_amdgcn_mfma_f32_16x16x32_f16(af, bf, acc[n], 0, 0, 0);
            }
        }
#pragma unroll
        for (int n = 0; n < 6; ++n)
#pragma unroll
            for (int j = 0; j < 4; ++j)
                act[(q*4 + j)*136 + n*16 + col] = (_Float16)fmaxf(acc[n][j], 0.f);

        // ---- L3: y = relu(h2 @ W3^T + b3), B-frags from registers ----
        f32x4 acy; acy[0] = b3v; acy[1] = b3v; acy[2] = b3v; acy[3] = b3v;
#pragma unroll
        for (int t3 = 0; t3 < 3; ++t3) {
            f16x8 af = *(const f16x8*)((const char*)act + col*272 + t3*64 + q*16);
            acy = __builtin_amdgcn_mfma_f32_16x16x32_f16(af, w3f[t3], acy, 0, 0, 0);
        }
        if (col < 5) {
#pragma unroll
            for (int j = 0; j < 4; ++j)
                syw[(q*4 + j)*6 + col] = fmaxf(acy[j], 0.f);
        }

        // ---- epilogue: normalize + mask + rescue flag (lanes 0..15) ----
        if (lane < 16) {
            long grow = rowbase + lane;
            if (grow < nrows) {
                float y0 = syw[lane*6 + 0], y1 = syw[lane*6 + 1],
                      y2 = syw[lane*6 + 2], y3 = syw[lane*6 + 3],
                      y4 = syw[lane*6 + 4];
                float ss = y0*y0 + y1*y1 + y2*y2 + y3*y3 + y4*y4;
                float inv = 1.0f / fmaxf(sqrtf(ss), 1e-12f);
                const float* xp = x + grow * 5;
                float* op = out + grow * 5;
                op[0] = (xp[0] != 0.f) ? 0.f : y0 * inv;
                op[1] = (xp[1] != 0.f) ? 0.f : y1 * inv;
                op[2] = (xp[2] != 0.f) ? 0.f : y2 * inv;
                op[3] = (xp[3] != 0.f) ? 0.f : y3 * inv;
                op[4] = (xp[4] != 0.f) ? 0.f : y4 * inv;
                if (ss < TAU2) {
                    unsigned int idx = atomicAdd(cnt, 1u);
                    if (idx < cap) list[idx] = (unsigned int)grow;
                }
            }
        }
    }
}

// ---------------- rescue (exact f32, R3 structure) ----------------
template <int G0>
__device__ __forceinline__ void half_pass(
    const float xv[5],
    const float* __restrict__ W1, const float* __restrict__ b1,
    const float* __restrict__ W2T, const float* __restrict__ b2,
    const float* __restrict__ W3,
    float y[5])
{
    float acc[42];
#pragma unroll
    for (int g = 0; g < 42; ++g) acc[g] = b2[G0 + g];
    for (int h = 0; h < 120; ++h) {
        float a = b1[h];
        a = fmaf(W1[h*5 + 0], xv[0], a);
        a = fmaf(W1[h*5 + 1], xv[1], a);
        a = fmaf(W1[h*5 + 2], xv[2], a);
        a = fmaf(W1[h*5 + 3], xv[3], a);
        a = fmaf(W1[h*5 + 4], xv[4], a);
        a = fmaxf(a, 0.0f);
        const float* wr = W2T + h*84 + G0;
#pragma unroll
        for (int g = 0; g < 42; ++g) acc[g] = fmaf(wr[g], a, acc[g]);
    }
#pragma unroll
    for (int g = 0; g < 42; ++g) acc[g] = fmaxf(acc[g], 0.0f);
#pragma unroll
    for (int o = 0; o < 5; ++o) {
        const float* w3o = W3 + o*84 + G0;
        float ty = y[o];
#pragma unroll
        for (int g = 0; g < 42; ++g) ty = fmaf(w3o[g], acc[g], ty);
        y[o] = ty;
    }
}

__global__ __launch_bounds__(256) void rescue_kernel(
    const float* __restrict__ x,
    const float* __restrict__ W1, const float* __restrict__ b1,
    const char*  __restrict__ ws, const float* __restrict__ b2,
    const float* __restrict__ W3, const float* __restrict__ b3,
    float* __restrict__ out, unsigned int cap, int nrows)
{
    const unsigned int* cnt  = (const unsigned int*)(ws + CNT_OFF);
    const unsigned int* list = (const unsigned int*)(ws + LIST_OFF);
    const float* W2T = (const float*)(ws + W2T_OFF);
    unsigned int count = *cnt;
    if (count > cap) count = cap;

    for (unsigned int t = blockIdx.x * 256 + threadIdx.x;
         t < count; t += gridDim.x * 256) {
        long row = (long)list[t];
        if (row < 0 || row >= (long)nrows) continue;   // replay-safety guard

        const float* xr = x + row * 5;
        float xv[5];
#pragma unroll
        for (int i = 0; i < 5; ++i) xv[i] = xr[i];

        float y[5];
#pragma unroll
        for (int o = 0; o < 5; ++o) y[o] = b3[o];
        half_pass<0>(xv, W1, b1, W2T, b2, W3, y);
        half_pass<42>(xv, W1, b1, W2T, b2, W3, y);
#pragma unroll
        for (int o = 0; o < 5; ++o) y[o] = fmaxf(y[o], 0.0f);

        float ss = y[0]*y[0];
        ss = fmaf(y[1], y[1], ss);
        ss = fmaf(y[2], y[2], ss);
        ss = fmaf(y[3], y[3], ss);
        ss = fmaf(y[4], y[4], ss);
        float inv = 1.0f / fmaxf(sqrtf(ss), 1e-12f);
        float* op = out + row * 5;
#pragma unroll
        for (int o = 0; o < 5; ++o)
            op[o] = (xv[o] != 0.f) ? 0.f : y[o] * inv;
    }
}

// ---------------- launch ----------------
extern "C" void kernel_launch(void* const* d_in, const int* in_sizes, int n_in,
                              void* d_out, int out_size, void* d_ws, size_t ws_size,
                              hipStream_t stream) {
    const float* x  = (const float*)d_in[0];
    const float* W1 = (const float*)d_in[1];
    const float* b1 = (const float*)d_in[2];
    const float* W2 = (const float*)d_in[3];
    const float* b2 = (const float*)d_in[4];
    const float* W3 = (const float*)d_in[5];
    const float* b3 = (const float*)d_in[6];
    float* out = (float*)d_out;
    char* ws = (char*)d_ws;

    const int nrows = in_sizes[0] / 5;
    const int ntiles = (nrows + 15) / 16;
    unsigned int cap = (ws_size > (size_t)LIST_OFF + 4)
                       ? (unsigned int)((ws_size - LIST_OFF) / 4) : 0u;
    unsigned int* cnt  = (unsigned int*)(ws + CNT_OFF);
    unsigned int* list = (unsigned int*)(ws + LIST_OFF);

    pack_kernel<<<48, 256, 0, stream>>>(W1, W2, W3, ws);

    mfma_main<<<768, 256, 0, stream>>>(x, b1, b2, b3, ws, out,
                                       cnt, list, cap, nrows, ntiles);

    rescue_kernel<<<256, 256, 0, stream>>>(x, W1, b1, ws, b2, W3, b3,
                                           out, cap, nrows);
}

// Round 10
// 167.283 us; speedup vs baseline: 2.2585x; 1.0380x over previous
//
#include <hip/hip_runtime.h>

// Per-row MLP 5->120->84->5 + relu + L2-normalize + x!=0 mask.
// R10: zero-LDS MFMA kernel via swapped operands.
//   All layers compute TRANSPOSED outputs: h^T = mfma(W, act^T). Since A-frag
//   and B-frag share the lane layout (row/col=lane&15, k=(lane>>4)*8+j), the
//   D output (4 features of OWN board row per lane) feeds the next layer's
//   B-frag directly after relu+cvt -- provided the next W's k-order is
//   pre-permuted to match. pack_kernel emits exactly that permuted order:
//     feature(t, q, j') = 32t + 16*(j'>>2) + 4q + (j'&3)
//   Biases fold into augmented k-slots (xaug[5]=1 -> W1aug[.][5]=b1;
//   h1[120]==1 -> W2aug[.][120]=b2; h2[84]==1 -> W3aug[.][84]=b3).
//   W1/W2/W3 frags live in registers (35 f16x8 = 140 VGPR), loaded once per
//   persistent wave (~40 tiles/wave). No LDS, no barriers; y4 via __shfl.
// Rescue: rows with ||y||^2 < TAU2 recomputed exact-f32 (R3 structure).

typedef _Float16 f16x8 __attribute__((ext_vector_type(8)));
typedef float    f32x4 __attribute__((ext_vector_type(4)));

#define CNT_OFF  0
#define W2T_OFF  64          // f32[120*84]          -> ends 40384
#define W1A_OFF  40384       // f16[8][64][8]        -> ends 48576
#define W2A_OFF  48576       // f16[24][64][8]       -> ends 73152
#define W3A_OFF  73152       // f16[3][64][8]        -> ends 76224
#define LIST_OFF 76224
#define TAU2     0.0625f     // rescue if ||y||^2 < 0.25^2

// ---------------- pack ----------------
__global__ __launch_bounds__(256) void pack_kernel(
    const float* __restrict__ W1, const float* __restrict__ b1,
    const float* __restrict__ W2, const float* __restrict__ b2,
    const float* __restrict__ W3, const float* __restrict__ b3,
    char* __restrict__ ws)
{
    int i = blockIdx.x * 256 + threadIdx.x;
    if (i == 0) *(unsigned int*)(ws + CNT_OFF) = 0u;
    _Float16* W1a = (_Float16*)(ws + W1A_OFF);
    _Float16* W2a = (_Float16*)(ws + W2A_OFF);
    _Float16* W3a = (_Float16*)(ws + W3A_OFF);
    float*    W2T = (float*)(ws + W2T_OFF);

    // W1a[n][l][j]: A-frag of W1aug. feat = 16n + (l&15), k = (l>>4)*8 + j.
    if (i < 4096) {
        int n = i >> 9, l = (i >> 3) & 63, j = i & 7;
        int feat = 16*n + (l & 15);
        int k = (l >> 4) * 8 + j;
        float v = 0.f;
        if (feat < 120) {
            if (k < 5) v = W1[feat*5 + k];
            else if (k == 5) v = b1[feat];
        } else if (feat == 120 && k == 5) v = 1.f;
        W1a[i] = (_Float16)v;
    }
    // W2a[b=(n2*4+t4)][l][j']: A-frag of W2aug, k-permuted:
    //   f = 32*t4 + 16*(j'>>2) + 4*(l>>4) + (j'&3)
    if (i < 12288) {
        int b = i >> 9, l = (i >> 3) & 63, j = i & 7;
        int n2 = b >> 2, t4 = b & 3;
        int g = 16*n2 + (l & 15);
        int f = 32*t4 + 16*(j >> 2) + 4*(l >> 4) + (j & 3);
        float v = 0.f;
        if (g < 84) {
            if (f < 120) v = W2[g*120 + f];
            else if (f == 120) v = b2[g];
        } else if (g == 84 && f == 120) v = 1.f;
        W2a[i] = (_Float16)v;
    }
    // W3a[t3][l][j']: A-frag of W3aug, same k-permutation over h2 features.
    if (i < 1536) {
        int t3 = i >> 9, l = (i >> 3) & 63, j = i & 7;
        int o = l & 15;
        int f = 32*t3 + 16*(j >> 2) + 4*(l >> 4) + (j & 3);
        float v = 0.f;
        if (o < 5) {
            if (f < 84) v = W3[o*84 + f];
            else if (f == 84) v = b3[o];
        }
        W3a[i] = (_Float16)v;
    }
    // W2T for the f32 rescue path.
    if (i < 10080) { int g = i / 120, h = i - g*120; W2T[h*84 + g] = W2[i]; }
}

// ---------------- main (persistent, zero-LDS) ----------------
__global__ __launch_bounds__(256, 2) void mfma_main(
    const float* __restrict__ x, const char* __restrict__ ws,
    float* __restrict__ out,
    unsigned int* __restrict__ cnt, unsigned int* __restrict__ list,
    unsigned int cap, int nrows, int ntiles)
{
    const _Float16* W1a = (const _Float16*)(ws + W1A_OFF);
    const _Float16* W2a = (const _Float16*)(ws + W2A_OFF);
    const _Float16* W3a = (const _Float16*)(ws + W3A_OFF);

    const int tid  = threadIdx.x;
    const int w    = tid >> 6, lane = tid & 63;
    const int c    = lane & 15, q = lane >> 4;

    // persistent weight fragments (loaded once per wave)
    f16x8 w1f[8], w2f[24], w3f[3];
#pragma unroll
    for (int n = 0; n < 8; ++n)  w1f[n] = *(const f16x8*)(W1a + (n*64 + lane)*8);
#pragma unroll
    for (int b = 0; b < 24; ++b) w2f[b] = *(const f16x8*)(W2a + (b*64 + lane)*8);
#pragma unroll
    for (int t = 0; t < 3; ++t)  w3f[t] = *(const f16x8*)(W3a + (t*64 + lane)*8);

    const int gw = blockIdx.x * 4 + w;
    const int nw = gridDim.x * 4;
    for (int t = gw; t < ntiles; t += nw) {
        const long row = (long)t * 16 + c;

        // B-frag of xaug^T: lane holds xaug[c][k=q*8+j]; q==0: [x0..x4,1,0,0]
        float xv0 = 0.f, xv1 = 0.f, xv2 = 0.f, xv3 = 0.f, xv4 = 0.f;
        f16x8 ax;
#pragma unroll
        for (int j = 0; j < 8; ++j) ax[j] = (_Float16)0.f;
        if (q == 0 && row < nrows) {
            const float* xp = x + row * 5;
            xv0 = xp[0]; xv1 = xp[1]; xv2 = xp[2]; xv3 = xp[3]; xv4 = xp[4];
            ax[0] = (_Float16)xv0; ax[1] = (_Float16)xv1; ax[2] = (_Float16)xv2;
            ax[3] = (_Float16)xv3; ax[4] = (_Float16)xv4; ax[5] = (_Float16)1.f;
        }

        // ---- L1: d1[n] = W1aug . xaug^T (lane: feats 16n+4q+j of row c) ----
        f32x4 d1[8];
#pragma unroll
        for (int n = 0; n < 8; ++n)
            d1[n] = __builtin_amdgcn_mfma_f32_16x16x32_f16(
                w1f[n], ax, (f32x4){0.f, 0.f, 0.f, 0.f}, 0, 0, 0);

        // ---- pack h1 B-frags (relu + cvt), k-order matches W2a's perm ----
        f16x8 pb[4];
#pragma unroll
        for (int t4 = 0; t4 < 4; ++t4) {
#pragma unroll
            for (int j = 0; j < 4; ++j) {
                pb[t4][j]     = (_Float16)fmaxf(d1[2*t4][j],     0.f);
                pb[t4][j + 4] = (_Float16)fmaxf(d1[2*t4 + 1][j], 0.f);
            }
        }

        // ---- L2: acc[n2] = W2aug . h1^T ----
        f32x4 acc[6];
#pragma unroll
        for (int n2 = 0; n2 < 6; ++n2) acc[n2] = (f32x4){0.f, 0.f, 0.f, 0.f};
#pragma unroll
        for (int t4 = 0; t4 < 4; ++t4)
#pragma unroll
            for (int n2 = 0; n2 < 6; ++n2)
                acc[n2] = __builtin_amdgcn_mfma_f32_16x16x32_f16(
                    w2f[n2*4 + t4], pb[t4], acc[n2], 0, 0, 0);

        // ---- pack h2 B-frags ----
        f16x8 ph[3];
#pragma unroll
        for (int t3 = 0; t3 < 3; ++t3) {
#pragma unroll
            for (int j = 0; j < 4; ++j) {
                ph[t3][j]     = (_Float16)fmaxf(acc[2*t3][j],     0.f);
                ph[t3][j + 4] = (_Float16)fmaxf(acc[2*t3 + 1][j], 0.f);
            }
        }

        // ---- L3: acy = W3aug . h2^T (lane: outs 4q+j of row c) ----
        f32x4 acy = (f32x4){0.f, 0.f, 0.f, 0.f};
#pragma unroll
        for (int t3 = 0; t3 < 3; ++t3)
            acy = __builtin_amdgcn_mfma_f32_16x16x32_f16(
                w3f[t3], ph[t3], acy, 0, 0, 0);

        // ---- epilogue ----
        float r0 = fmaxf(acy[0], 0.f);
        float y4 = __shfl(r0, c + 16, 64);       // out4 lives in q==1, j==0
        if (q == 0 && row < nrows) {
            float y0 = r0;
            float y1 = fmaxf(acy[1], 0.f);
            float y2 = fmaxf(acy[2], 0.f);
            float y3 = fmaxf(acy[3], 0.f);
            float ss = y0*y0 + y1*y1 + y2*y2 + y3*y3 + y4*y4;
            float inv = 1.0f / fmaxf(sqrtf(ss), 1e-12f);
            float* op = out + row * 5;
            op[0] = (xv0 != 0.f) ? 0.f : y0 * inv;
            op[1] = (xv1 != 0.f) ? 0.f : y1 * inv;
            op[2] = (xv2 != 0.f) ? 0.f : y2 * inv;
            op[3] = (xv3 != 0.f) ? 0.f : y3 * inv;
            op[4] = (xv4 != 0.f) ? 0.f : y4 * inv;
            if (ss < TAU2) {
                unsigned int idx = atomicAdd(cnt, 1u);
                if (idx < cap) list[idx] = (unsigned int)row;
            }
        }
    }
}

// ---------------- rescue (exact f32, R3 structure) ----------------
template <int G0>
__device__ __forceinline__ void half_pass(
    const float xv[5],
    const float* __restrict__ W1, const float* __restrict__ b1,
    const float* __restrict__ W2T, const float* __restrict__ b2,
    const float* __restrict__ W3,
    float y[5])
{
    float acc[42];
#pragma unroll
    for (int g = 0; g < 42; ++g) acc[g] = b2[G0 + g];
    for (int h = 0; h < 120; ++h) {
        float a = b1[h];
        a = fmaf(W1[h*5 + 0], xv[0], a);
        a = fmaf(W1[h*5 + 1], xv[1], a);
        a = fmaf(W1[h*5 + 2], xv[2], a);
        a = fmaf(W1[h*5 + 3], xv[3], a);
        a = fmaf(W1[h*5 + 4], xv[4], a);
        a = fmaxf(a, 0.0f);
        const float* wr = W2T + h*84 + G0;
#pragma unroll
        for (int g = 0; g < 42; ++g) acc[g] = fmaf(wr[g], a, acc[g]);
    }
#pragma unroll
    for (int g = 0; g < 42; ++g) acc[g] = fmaxf(acc[g], 0.0f);
#pragma unroll
    for (int o = 0; o < 5; ++o) {
        const float* w3o = W3 + o*84 + G0;
        float ty = y[o];
#pragma unroll
        for (int g = 0; g < 42; ++g) ty = fmaf(w3o[g], acc[g], ty);
        y[o] = ty;
    }
}

__global__ __launch_bounds__(256) void rescue_kernel(
    const float* __restrict__ x,
    const float* __restrict__ W1, const float* __restrict__ b1,
    const char*  __restrict__ ws, const float* __restrict__ b2,
    const float* __restrict__ W3, const float* __restrict__ b3,
    float* __restrict__ out, unsigned int cap, int nrows)
{
    const unsigned int* cnt  = (const unsigned int*)(ws + CNT_OFF);
    const unsigned int* list = (const unsigned int*)(ws + LIST_OFF);
    const float* W2T = (const float*)(ws + W2T_OFF);
    unsigned int count = *cnt;
    if (count > cap) count = cap;

    for (unsigned int t = blockIdx.x * 256 + threadIdx.x;
         t < count; t += gridDim.x * 256) {
        long row = (long)list[t];
        if (row < 0 || row >= (long)nrows) continue;   // replay-safety guard

        const float* xr = x + row * 5;
        float xv[5];
#pragma unroll
        for (int i = 0; i < 5; ++i) xv[i] = xr[i];

        float y[5];
#pragma unroll
        for (int o = 0; o < 5; ++o) y[o] = b3[o];
        half_pass<0>(xv, W1, b1, W2T, b2, W3, y);
        half_pass<42>(xv, W1, b1, W2T, b2, W3, y);
#pragma unroll
        for (int o = 0; o < 5; ++o) y[o] = fmaxf(y[o], 0.0f);

        float ss = y[0]*y[0];
        ss = fmaf(y[1], y[1], ss);
        ss = fmaf(y[2], y[2], ss);
        ss = fmaf(y[3], y[3], ss);
        ss = fmaf(y[4], y[4], ss);
        float inv = 1.0f / fmaxf(sqrtf(ss), 1e-12f);
        float* op = out + row * 5;
#pragma unroll
        for (int o = 0; o < 5; ++o)
            op[o] = (xv[o] != 0.f) ? 0.f : y[o] * inv;
    }
}

// ---------------- launch ----------------
extern "C" void kernel_launch(void* const* d_in, const int* in_sizes, int n_in,
                              void* d_out, int out_size, void* d_ws, size_t ws_size,
                              hipStream_t stream) {
    const float* x  = (const float*)d_in[0];
    const float* W1 = (const float*)d_in[1];
    const float* b1 = (const float*)d_in[2];
    const float* W2 = (const float*)d_in[3];
    const float* b2 = (const float*)d_in[4];
    const float* W3 = (const float*)d_in[5];
    const float* b3 = (const float*)d_in[6];
    float* out = (float*)d_out;
    char* ws = (char*)d_ws;

    const int nrows = in_sizes[0] / 5;
    const int ntiles = (nrows + 15) / 16;
    unsigned int cap = (ws_size > (size_t)LIST_OFF + 4)
                       ? (unsigned int)((ws_size - LIST_OFF) / 4) : 0u;
    unsigned int* cnt  = (unsigned int*)(ws + CNT_OFF);
    unsigned int* list = (unsigned int*)(ws + LIST_OFF);

    pack_kernel<<<48, 256, 0, stream>>>(W1, b1, W2, b2, W3, b3, ws);

    mfma_main<<<512, 256, 0, stream>>>(x, ws, out, cnt, list, cap,
                                       nrows, ntiles);

    rescue_kernel<<<256, 256, 0, stream>>>(x, W1, b1, ws, b2, W3, b3,
                                           out, cap, nrows);
}